// Round 1
// baseline (195.919 us; speedup 1.0000x reference)
//
#include <hip/hip_runtime.h>
#include <hip/hip_bf16.h>
#include <stdint.h>

typedef __attribute__((ext_vector_type(4))) float f32x4;
typedef __attribute__((ext_vector_type(8))) __bf16 bf16x8;

#define BATCH 8
#define CIN 64
#define HW 96
#define OCH 128
#define NF 54
#define KP 64
#define TILE_H 8
#define TILE_W 16
#define CHBYTES (OCH * KP * 2)   // 16384 B per channel weight tile

// ---------------- weight prep: fp32 [128][64][54] -> bf16 swizzled [c][oc][k64]
__global__ __launch_bounds__(256) void prep_w(const float* __restrict__ w,
                                              char* __restrict__ wb) {
    int idx = blockIdx.x * 256 + threadIdx.x;   // 64*128*32 = 262144 exactly
    int j  = idx & 31;            // k-pair index: k = 2j, 2j+1
    int oc = (idx >> 5) & 127;
    int c  = idx >> 12;
    float v0 = (2*j     < NF) ? w[(oc*CIN + c)*NF + 2*j    ] : 0.f;
    float v1 = (2*j + 1 < NF) ? w[(oc*CIN + c)*NF + 2*j + 1] : 0.f;
    int off = (oc*128 + 4*j) ^ ((oc & 7) << 4);   // XOR-swizzle within 128B row
    union { __bf16 b[2]; uint32_t u; } pk;
    pk.b[0] = (__bf16)v0; pk.b[1] = (__bf16)v1;
    *(uint32_t*)(wb + (size_t)c * CHBYTES + off) = pk.u;
}

// ---------------- async global->LDS 16B
__device__ __forceinline__ void gload_lds16(const void* g, void* l) {
    __builtin_amdgcn_global_load_lds(
        (const __attribute__((address_space(1))) void*)g,
        (__attribute__((address_space(3))) void*)l, 16, 0, 0);
}

__device__ __forceinline__ void load_patch(const float* xb, int c, int hh0, int ww0,
                                           float v[9]) {
    const float* xc = xb + (size_t)c * HW * HW;
#pragma unroll
    for (int dy = 0; dy < 3; dy++) {
#pragma unroll
        for (int dx = 0; dx < 3; dx++) {
            int hh = hh0 + dy - 1, ww = ww0 + dx - 1;
            bool ok = ((unsigned)hh < HW) && ((unsigned)ww < HW);
            v[dy*3 + dx] = ok ? xc[hh*HW + ww] : 0.f;
        }
    }
}

__device__ __forceinline__ void build_write(char* buf, int p, const float v[9]) {
    bf16x8 fb[7];
#pragma unroll
    for (int i = 0; i < 9; i++) {
        fb[i >> 3][i & 7] = (__bf16)v[i];
        int s = 9 + i;
        fb[s >> 3][s & 7] = (__bf16)(v[i] * v[i]);
    }
    constexpr int PI[36] = {0,1,2,3,4,5,6,7, 0,1,2,3,4,5,6, 0,1,2,3,4,5,
                            0,1,2,3,4, 0,1,2,3, 0,1,2, 0,1, 0};
    constexpr int PJ[36] = {1,2,3,4,5,6,7,8, 2,3,4,5,6,7,8, 3,4,5,6,7,8,
                            4,5,6,7,8, 5,6,7,8, 6,7,8, 7,8, 8};
#pragma unroll
    for (int k = 0; k < 36; k++) {
        int s = 18 + k;
        fb[s >> 3][s & 7] = (__bf16)(v[PI[k]] * v[PJ[k]]);
    }
    fb[6][6] = (__bf16)0.f; fb[6][7] = (__bf16)0.f;   // f54,f55 pad
#pragma unroll
    for (int i = 0; i < 7; i++) {
        int off = (p*128 + i*16) ^ ((p & 7) << 4);
        *(bf16x8*)(buf + off) = fb[i];
    }
}

// ---------------- main: D[oc][pos] = sum_k W[oc][k] * F[k][pos]
__global__ __launch_bounds__(256, 2) void socg_main(const float* __restrict__ x,
                                                    const char* __restrict__ wbg,
                                                    float* __restrict__ out) {
    __shared__ __align__(16) char sfeat[2][16384];   // [pos 128][k 64] bf16, swizzled
    __shared__ __align__(16) char swb[2][16384];     // [oc 128][k 64] bf16, swizzled

    const int tid = threadIdx.x;
    const int lane = tid & 63;
    const int wv = tid >> 6;
    const int l15 = lane & 15;
    const int lg = lane >> 4;

    const int bid = blockIdx.x;       // 576 = 8 imgs * 12 * 6
    const int bimg = bid / 72;
    const int rem = bid - bimg * 72;
    const int h0 = (rem / 6) * TILE_H;
    const int w0 = (rem % 6) * TILE_W;

    const int wave_oc  = (wv >> 1) * 64;
    const int wave_pos = (wv & 1) * 64;

    // zero the K-pad columns (bytes 112..127 of each row) of both feat buffers
    for (int i = tid; i < 1024; i += 256) {
        int buf = i >> 9; int r = (i >> 2) & 127; int dw = i & 3;
        int off = (r*128 + 112 + dw*4) ^ ((r & 7) << 4);
        *(uint32_t*)(sfeat[buf] + off) = 0u;
    }

    // stage weights for channel 0
    for (int i = wv; i < 16; i += 4)
        gload_lds16(wbg + (size_t)0*CHBYTES + i*1024 + lane*16, swb[0] + i*1024);

    f32x4 acc[4][4];
#pragma unroll
    for (int a = 0; a < 4; a++)
#pragma unroll
        for (int b = 0; b < 4; b++) acc[a][b] = (f32x4){0.f, 0.f, 0.f, 0.f};

    const int p = tid;                 // builder position (tid < 128)
    const int ty = (p >> 4) & 7, tx = p & 15;
    const float* xb = x + (size_t)bimg * CIN * HW * HW;

    float v[9];
    if (tid < 128) {
        load_patch(xb, 0, h0 + ty, w0 + tx, v);
        build_write(sfeat[0], p, v);
    }
    __syncthreads();

    for (int c = 0; c < CIN; c++) {
        const int cur = c & 1, nxt = cur ^ 1;
        if (c + 1 < CIN) {
            for (int i = wv; i < 16; i += 4)
                gload_lds16(wbg + (size_t)(c+1)*CHBYTES + i*1024 + lane*16,
                            swb[nxt] + i*1024);
            if (tid < 128) load_patch(xb, c + 1, h0 + ty, w0 + tx, v);
        }
        // MFMA on current buffers
#pragma unroll
        for (int kc = 0; kc < 2; kc++) {
            bf16x8 af[4], bfr[4];
#pragma unroll
            for (int oi = 0; oi < 4; oi++) {
                int row = wave_oc + oi*16 + l15;
                int off = (row*128 + kc*64 + lg*16) ^ ((row & 7) << 4);
                af[oi] = *(const bf16x8*)(swb[cur] + off);
            }
#pragma unroll
            for (int pj = 0; pj < 4; pj++) {
                int row = wave_pos + pj*16 + l15;
                int off = (row*128 + kc*64 + lg*16) ^ ((row & 7) << 4);
                bfr[pj] = *(const bf16x8*)(sfeat[cur] + off);
            }
#pragma unroll
            for (int oi = 0; oi < 4; oi++)
#pragma unroll
                for (int pj = 0; pj < 4; pj++)
                    acc[oi][pj] = __builtin_amdgcn_mfma_f32_16x16x32_bf16(
                        af[oi], bfr[pj], acc[oi][pj], 0, 0, 0);
        }
        if (c + 1 < CIN && tid < 128) build_write(sfeat[nxt], p, v);
        __syncthreads();
    }

    // store: D row = oc (lg*4 + r within 16-frag), col = pos (l15) -> coalesced in w
#pragma unroll
    for (int oi = 0; oi < 4; oi++) {
#pragma unroll
        for (int pj = 0; pj < 4; pj++) {
            int pos = wave_pos + pj*16 + l15;
            int hh = h0 + (pos >> 4), ww = w0 + (pos & 15);
#pragma unroll
            for (int r = 0; r < 4; r++) {
                int oc = wave_oc + oi*16 + lg*4 + r;
                out[(((size_t)bimg*OCH + oc)*HW + hh)*HW + ww] = acc[oi][pj][r];
            }
        }
    }
}

extern "C" void kernel_launch(void* const* d_in, const int* in_sizes, int n_in,
                              void* d_out, int out_size, void* d_ws, size_t ws_size,
                              hipStream_t stream) {
    const float* x = (const float*)d_in[0];
    const float* w = (const float*)d_in[1];
    float* out = (float*)d_out;
    char* wb = (char*)d_ws;   // needs 64*16384 = 1 MiB
    hipLaunchKernelGGL(prep_w, dim3(1024), dim3(256), 0, stream, w, wb);
    hipLaunchKernelGGL(socg_main, dim3(576), dim3(256), 0, stream, x, wb, out);
}

// Round 2
// 173.453 us; speedup vs baseline: 1.1295x; 1.1295x over previous
//
#include <hip/hip_runtime.h>
#include <hip/hip_bf16.h>
#include <stdint.h>

typedef __attribute__((ext_vector_type(16))) float f32x16;
typedef __attribute__((ext_vector_type(8))) __bf16 bf16x8;

#define CIN 64
#define HW 96
#define OCH 128
#define NF 54

// ---- weight prep: w fp32 [oc 128][c 64][54] -> wb bf16 fragment-native:
// elem index = ((c*4 + kc)*2 + hi)*1024 + oc*8 + i   (k = kc*16 + hi*8 + i, pad k>=54 -> 0)
__global__ __launch_bounds__(256) void prep_w(const float* __restrict__ w,
                                              __bf16* __restrict__ wb) {
    int idx = blockIdx.x * 256 + threadIdx.x;   // 64*128*32 = 262144
    int j  = idx & 31;             // k-pair: k = 2j, 2j+1
    int oc = (idx >> 5) & 127;
    int c  = idx >> 12;
    int k  = 2 * j;
    int kc = k >> 4, hi = (k >> 3) & 1, i = k & 7;
    float v0 = (k     < NF) ? w[(oc*CIN + c)*NF + k    ] : 0.f;
    float v1 = (k + 1 < NF) ? w[(oc*CIN + c)*NF + k + 1] : 0.f;
    size_t off = ((size_t)(c*8 + kc*2 + hi))*1024 + oc*8 + i;
    union { __bf16 b[2]; uint32_t u; } pk;
    pk.b[0] = (__bf16)v0; pk.b[1] = (__bf16)v1;
    *(uint32_t*)((char*)wb + off*2) = pk.u;     // i even -> 4B aligned
}

// cross-product pair tables (PM_cross order, j=1..8, i=0..8-j)
__device__ __forceinline__ constexpr int PIc(int k) {
    constexpr int t[36] = {0,1,2,3,4,5,6,7, 0,1,2,3,4,5,6, 0,1,2,3,4,5,
                           0,1,2,3,4, 0,1,2,3, 0,1,2, 0,1, 0};
    return t[k];
}
__device__ __forceinline__ constexpr int PJc(int k) {
    constexpr int t[36] = {1,2,3,4,5,6,7,8, 2,3,4,5,6,7,8, 3,4,5,6,7,8,
                           4,5,6,7,8, 5,6,7,8, 6,7,8, 7,8, 8};
    return t[k];
}

// build 8 consecutive features k = K0..K0+7 for one position (v = 9 patch vals)
template<int K0>
__device__ __forceinline__ bf16x8 make_frag(const float* v) {
    bf16x8 r;
#pragma unroll
    for (int i = 0; i < 8; i++) {
        const int k = K0 + i;
        float f;
        if constexpr (false) {}
        f = (k < 9)  ? v[k]
          : (k < 18) ? v[k-9] * v[k-9]
          : (k < 54) ? v[PIc(k-18)] * v[PJc(k-18)]
          : 0.f;
        r[i] = (__bf16)f;
    }
    return r;
}

// ---- main: no LDS, no barriers. Block = 4 waves, tile 128 pos x 128 oc.
// Wave = 64 pos x 64 oc. A = weights (row=oc), B = features (col=pos), both
// per mfma_f32_32x32x16_bf16 layout: A/B lane: row/col = lane&31, k = (lane>>5)*8+i;
// D: col = lane&31, row = (reg&3) + 8*(reg>>2) + 4*(lane>>5).
__global__ __launch_bounds__(256, 2) void socg_main(const float* __restrict__ x,
                                                    const __bf16* __restrict__ wb,
                                                    float* __restrict__ out) {
    const int tid  = threadIdx.x;
    const int lane = tid & 63;
    const int wv   = tid >> 6;
    const int hi   = lane >> 5;
    const int l31  = lane & 31;

    const int bid  = blockIdx.x;          // 576 = 8 imgs * 12 * 6
    const int bimg = bid / 72;
    const int rem  = bid - bimg * 72;
    const int h0   = (rem / 6) * 8;
    const int w0   = (rem % 6) * 16;

    const int wave_pos = (wv >> 1) * 64;
    const int wave_oc  = (wv & 1) * 64;

    // lane owns positions p0 (rows 0-2 of its 5-row window) and p0+32 (rows 2-4)
    const int p0 = wave_pos + l31;
    const int hA = h0 + (p0 >> 4);
    const int wA = w0 + (p0 & 15);

    int   off[15];
    float msk[15];
#pragma unroll
    for (int rr = 0; rr < 5; rr++)
#pragma unroll
        for (int cc = 0; cc < 3; cc++) {
            int hh = hA - 1 + rr, ww = wA - 1 + cc;
            bool ok = ((unsigned)hh < HW) && ((unsigned)ww < HW);
            int hc = hh < 0 ? 0 : (hh > HW-1 ? HW-1 : hh);
            int wc = ww < 0 ? 0 : (ww > HW-1 ? HW-1 : ww);
            off[rr*3 + cc] = hc * HW + wc;
            msk[rr*3 + cc] = ok ? 1.f : 0.f;
        }

    const float* xb = x + (size_t)bimg * CIN * HW * HW;

    f32x16 acc[2][2];
#pragma unroll
    for (int a = 0; a < 2; a++)
#pragma unroll
        for (int b = 0; b < 2; b++)
#pragma unroll
            for (int r = 0; r < 16; r++) acc[a][b][r] = 0.f;

    float rA[15], rB[15];
#pragma unroll
    for (int i = 0; i < 15; i++) rA[i] = xb[off[i]];   // patches for c = 0

    auto body = [&](float (&rc)[15], float (&rn)[15], int c) {
        // A-fragments for this channel (global, L1/L2-hot, coalesced 512B runs)
        const __bf16* wc_ = wb + (size_t)c * 8192;
        bf16x8 Af[4][2];
#pragma unroll
        for (int kc = 0; kc < 4; kc++)
#pragma unroll
            for (int os = 0; os < 2; os++)
                Af[kc][os] = *(const bf16x8*)(wc_ + (kc*2 + hi)*1024
                                              + (wave_oc + os*32 + l31)*8);
        // prefetch next channel's patches
        if (c + 1 < CIN) {
            const float* xn = xb + (size_t)(c + 1) * HW * HW;
#pragma unroll
            for (int i = 0; i < 15; i++) rn[i] = xn[off[i]];
        }
        // masked patch window; v(ps0) = q[0..8], v(ps1) = q[6..14]
        float q[15];
#pragma unroll
        for (int i = 0; i < 15; i++) q[i] = rc[i] * msk[i];

        // B-fragments in registers: lane's k-half is (lane>>5)*8 within each K=16 step
        bf16x8 Bf[2][4];
        if (hi == 0) {
            Bf[0][0] = make_frag<0 >(q);     Bf[0][1] = make_frag<16>(q);
            Bf[0][2] = make_frag<32>(q);     Bf[0][3] = make_frag<48>(q);
            Bf[1][0] = make_frag<0 >(q + 6); Bf[1][1] = make_frag<16>(q + 6);
            Bf[1][2] = make_frag<32>(q + 6); Bf[1][3] = make_frag<48>(q + 6);
        } else {
            Bf[0][0] = make_frag<8 >(q);     Bf[0][1] = make_frag<24>(q);
            Bf[0][2] = make_frag<40>(q);     Bf[0][3] = make_frag<56>(q);
            Bf[1][0] = make_frag<8 >(q + 6); Bf[1][1] = make_frag<24>(q + 6);
            Bf[1][2] = make_frag<40>(q + 6); Bf[1][3] = make_frag<56>(q + 6);
        }
#pragma unroll
        for (int kc = 0; kc < 4; kc++)
#pragma unroll
            for (int os = 0; os < 2; os++)
#pragma unroll
                for (int ps = 0; ps < 2; ps++)
                    acc[ps][os] = __builtin_amdgcn_mfma_f32_32x32x16_bf16(
                        Af[kc][os], Bf[ps][kc], acc[ps][os], 0, 0, 0);
    };

    for (int c2 = 0; c2 < CIN; c2 += 2) {
        body(rA, rB, c2);
        body(rB, rA, c2 + 1);
    }

    // epilogue: D col = pos (lane&31), row = (r&3) + 8*(r>>2) + 4*hi
#pragma unroll
    for (int ps = 0; ps < 2; ps++) {
        const int p  = wave_pos + ps*32 + l31;
        const int hh = h0 + (p >> 4);
        const int ww = w0 + (p & 15);
#pragma unroll
        for (int os = 0; os < 2; os++)
#pragma unroll
            for (int r = 0; r < 16; r++) {
                int oc = wave_oc + os*32 + (r & 3) + 8*(r >> 2) + 4*hi;
                out[(((size_t)bimg*OCH + oc)*HW + hh)*HW + ww] = acc[ps][os][r];
            }
    }
}

extern "C" void kernel_launch(void* const* d_in, const int* in_sizes, int n_in,
                              void* d_out, int out_size, void* d_ws, size_t ws_size,
                              hipStream_t stream) {
    const float* x = (const float*)d_in[0];
    const float* w = (const float*)d_in[1];
    float* out = (float*)d_out;
    __bf16* wbf = (__bf16*)d_ws;   // 64*8192*2 = 1 MiB
    hipLaunchKernelGGL(prep_w, dim3(1024), dim3(256), 0, stream, w, wbf);
    hipLaunchKernelGGL(socg_main, dim3(576), dim3(256), 0, stream, x, wbf, out);
}

// Round 3
// 165.614 us; speedup vs baseline: 1.1830x; 1.0473x over previous
//
#include <hip/hip_runtime.h>
#include <hip/hip_bf16.h>
#include <stdint.h>

typedef __attribute__((ext_vector_type(16))) float f32x16;
typedef __attribute__((ext_vector_type(8))) __bf16 bf16x8;

#define CIN 64
#define HW 96
#define OCH 128
#define NF 54

// ---- weight prep: w fp32 [oc 128][c 64][54] -> wb bf16 fragment-native:
// elem index = ((c*4 + kc)*2 + hi)*1024 + oc*8 + i   (k = kc*16 + hi*8 + i, pad k>=54 -> 0)
__global__ __launch_bounds__(256) void prep_w(const float* __restrict__ w,
                                              __bf16* __restrict__ wb) {
    int idx = blockIdx.x * 256 + threadIdx.x;   // 64*128*32 = 262144
    int j  = idx & 31;             // k-pair: k = 2j, 2j+1
    int oc = (idx >> 5) & 127;
    int c  = idx >> 12;
    int k  = 2 * j;
    int kc = k >> 4, hi = (k >> 3) & 1, i = k & 7;
    float v0 = (k     < NF) ? w[(oc*CIN + c)*NF + k    ] : 0.f;
    float v1 = (k + 1 < NF) ? w[(oc*CIN + c)*NF + k + 1] : 0.f;
    size_t off = ((size_t)(c*8 + kc*2 + hi))*1024 + oc*8 + i;
    union { __bf16 b[2]; uint32_t u; } pk;
    pk.b[0] = (__bf16)v0; pk.b[1] = (__bf16)v1;
    *(uint32_t*)((char*)wb + off*2) = pk.u;     // i even -> 4B aligned
}

// cross-product pair tables (PM_cross order, j=1..8, i=0..8-j)
__device__ __forceinline__ constexpr int PIc(int k) {
    constexpr int t[36] = {0,1,2,3,4,5,6,7, 0,1,2,3,4,5,6, 0,1,2,3,4,5,
                           0,1,2,3,4, 0,1,2,3, 0,1,2, 0,1, 0};
    return t[k];
}
__device__ __forceinline__ constexpr int PJc(int k) {
    constexpr int t[36] = {1,2,3,4,5,6,7,8, 2,3,4,5,6,7,8, 3,4,5,6,7,8,
                           4,5,6,7,8, 5,6,7,8, 6,7,8, 7,8, 8};
    return t[k];
}

__device__ __forceinline__ float featf(int k, const float* q) {
    return (k < 9)  ? q[k]
         : (k < 18) ? q[k-9] * q[k-9]
         : (k < 54) ? q[PIc(k-18)] * q[PJc(k-18)]
         : 0.f;
}

// ---- main: no LDS, no barriers, no divergent feature build.
// Wave = 32 pos x 64 oc. A = weights (row=oc), B = features (col=pos),
// mfma_f32_32x32x16_bf16: A/B lane: row/col = lane&31, k = (lane>>5)*8+i;
// D: col = lane&31, row = (reg&3) + 8*(reg>>2) + 4*(lane>>5).
__global__ __launch_bounds__(256, 4) void socg_main(const float* __restrict__ x,
                                                    const __bf16* __restrict__ wb,
                                                    float* __restrict__ out) {
    const int tid  = threadIdx.x;
    const int lane = tid & 63;
    const int wv   = tid >> 6;
    const int hi   = lane >> 5;
    const int l31  = lane & 31;

    const int bid  = blockIdx.x;          // 1152 = 8 imgs * 24 * 6
    const int bimg = bid / 144;
    const int rem  = bid - bimg * 144;
    const int h0   = (rem / 6) * 4;       // block: 4 rows x 16 cols, 128 oc
    const int w0   = (rem % 6) * 16;

    const int wave_oc = (wv & 1) * 64;    // wave: 32 pos x 64 oc
    const int prow    = (wv >> 1) * 2;

    // lane's single position
    const int hA = h0 + prow + (l31 >> 4);
    const int wA = w0 + (l31 & 15);

    int   off[9];
    float msk[9];
#pragma unroll
    for (int rr = 0; rr < 3; rr++)
#pragma unroll
        for (int cc = 0; cc < 3; cc++) {
            int hh = hA - 1 + rr, ww = wA - 1 + cc;
            bool ok = ((unsigned)hh < HW) && ((unsigned)ww < HW);
            int hc = hh < 0 ? 0 : (hh > HW-1 ? HW-1 : hh);
            int wc = ww < 0 ? 0 : (ww > HW-1 ? HW-1 : ww);
            off[rr*3 + cc] = hc * HW + wc;
            msk[rr*3 + cc] = ok ? 1.f : 0.f;
        }

    const float* xb = x + (size_t)bimg * CIN * HW * HW;

    f32x16 acc[2];
#pragma unroll
    for (int os = 0; os < 2; os++)
#pragma unroll
        for (int r = 0; r < 16; r++) acc[os][r] = 0.f;

    float rA[9], rB[9];
#pragma unroll
    for (int i = 0; i < 9; i++) rA[i] = xb[off[i]];   // patches for c = 0

    auto body = [&](float (&rc)[9], float (&rn)[9], int c) {
        // prefetch next channel's 3x3 window
        if (c + 1 < CIN) {
            const float* xn = xb + (size_t)(c + 1) * HW * HW;
#pragma unroll
            for (int i = 0; i < 9; i++) rn[i] = xn[off[i]];
        }
        float q[9];
#pragma unroll
        for (int i = 0; i < 9; i++) q[i] = rc[i] * msk[i];

        const __bf16* wc_ = wb + (size_t)c * 8192 + hi * 1024;
#pragma unroll
        for (int kc = 0; kc < 4; kc++) {
            // uniform build of features kc*16 .. kc*16+15 (both k-halves)
            float f[16];
#pragma unroll
            for (int t = 0; t < 16; t++) f[t] = featf(kc*16 + t, q);
            // pack to 8 bf16-pairs
            uint32_t P[8];
#pragma unroll
            for (int j = 0; j < 8; j++) {
                union { __bf16 b[2]; uint32_t u; } pk;
                pk.b[0] = (__bf16)f[2*j]; pk.b[1] = (__bf16)f[2*j+1];
                P[j] = pk.u;
            }
            // lane picks its k-half: 4 cndmask
            union { uint32_t u[4]; bf16x8 v; } tb;
#pragma unroll
            for (int j = 0; j < 4; j++) tb.u[j] = hi ? P[4+j] : P[j];

            const __bf16* wk = wc_ + kc * 2048;
            bf16x8 A0 = *(const bf16x8*)(wk + (wave_oc      + l31) * 8);
            bf16x8 A1 = *(const bf16x8*)(wk + (wave_oc + 32 + l31) * 8);
            acc[0] = __builtin_amdgcn_mfma_f32_32x32x16_bf16(A0, tb.v, acc[0], 0, 0, 0);
            acc[1] = __builtin_amdgcn_mfma_f32_32x32x16_bf16(A1, tb.v, acc[1], 0, 0, 0);
        }
    };

    for (int c2 = 0; c2 < CIN; c2 += 2) {
        body(rA, rB, c2);
        body(rB, rA, c2 + 1);
    }

    // epilogue: D col = pos (lane&31), row = (r&3) + 8*(r>>2) + 4*hi
    const int hh = hA, ww = wA;
#pragma unroll
    for (int os = 0; os < 2; os++)
#pragma unroll
        for (int r = 0; r < 16; r++) {
            int oc = wave_oc + os*32 + (r & 3) + 8*(r >> 2) + 4*hi;
            out[(((size_t)bimg*OCH + oc)*HW + hh)*HW + ww] = acc[os][r];
        }
}

extern "C" void kernel_launch(void* const* d_in, const int* in_sizes, int n_in,
                              void* d_out, int out_size, void* d_ws, size_t ws_size,
                              hipStream_t stream) {
    const float* x = (const float*)d_in[0];
    const float* w = (const float*)d_in[1];
    float* out = (float*)d_out;
    __bf16* wbf = (__bf16*)d_ws;   // 64*8192*2 = 1 MiB
    hipLaunchKernelGGL(prep_w, dim3(1024), dim3(256), 0, stream, w, wbf);
    hipLaunchKernelGGL(socg_main, dim3(1152), dim3(256), 0, stream, x, wbf, out);
}

// Round 4
// 150.286 us; speedup vs baseline: 1.3036x; 1.1020x over previous
//
#include <hip/hip_runtime.h>
#include <hip/hip_bf16.h>
#include <stdint.h>

typedef __attribute__((ext_vector_type(16))) float f32x16;
typedef __attribute__((ext_vector_type(8))) __bf16 bf16x8;

#define CIN 64
#define HW 96
#define OCH 128
#define NF 54

// ---- weight prep: w fp32 [oc 128][c 64][54] -> wb bf16 fragment-native:
// elem index = ((c*4 + kc)*2 + hi)*1024 + oc*8 + i   (k = kc*16 + hi*8 + i, pad k>=54 -> 0)
__global__ __launch_bounds__(256) void prep_w(const float* __restrict__ w,
                                              __bf16* __restrict__ wb) {
    int idx = blockIdx.x * 256 + threadIdx.x;   // 64*128*32 = 262144
    int j  = idx & 31;             // k-pair: k = 2j, 2j+1
    int oc = (idx >> 5) & 127;
    int c  = idx >> 12;
    int k  = 2 * j;
    int kc = k >> 4, hi = (k >> 3) & 1, i = k & 7;
    float v0 = (k     < NF) ? w[(oc*CIN + c)*NF + k    ] : 0.f;
    float v1 = (k + 1 < NF) ? w[(oc*CIN + c)*NF + k + 1] : 0.f;
    size_t off = ((size_t)(c*8 + kc*2 + hi))*1024 + oc*8 + i;
    union { __bf16 b[2]; uint32_t u; } pk;
    pk.b[0] = (__bf16)v0; pk.b[1] = (__bf16)v1;
    *(uint32_t*)((char*)wb + off*2) = pk.u;     // i even -> 4B aligned
}

// cross-product pair tables (PM_cross order, j=1..8, i=0..8-j)
__device__ __forceinline__ constexpr int PIc(int k) {
    constexpr int t[36] = {0,1,2,3,4,5,6,7, 0,1,2,3,4,5,6, 0,1,2,3,4,5,
                           0,1,2,3,4, 0,1,2,3, 0,1,2, 0,1, 0};
    return t[k];
}
__device__ __forceinline__ constexpr int PJc(int k) {
    constexpr int t[36] = {1,2,3,4,5,6,7,8, 2,3,4,5,6,7,8, 3,4,5,6,7,8,
                           4,5,6,7,8, 5,6,7,8, 6,7,8, 7,8, 8};
    return t[k];
}

__device__ __forceinline__ float featv(int k, const float* q) {
    return (k < 9)  ? q[k]
         : (k < 18) ? q[k-9] * q[k-9]
         : (k < 54) ? q[PIc(k-18)] * q[PJc(k-18)]
         : 0.f;
}

// lane picks its k-half pairs for K-group kc: hi=0 -> P[kc*8+0..3], hi=1 -> P[kc*8+4..7]
__device__ __forceinline__ bf16x8 selpair(const uint32_t* P, int kc, int hi) {
    union { uint32_t u[4]; bf16x8 v; } t;
#pragma unroll
    for (int j = 0; j < 4; j++) t.u[j] = hi ? P[kc*8 + 4 + j] : P[kc*8 + j];
    return t.v;
}

// ---- main: no LDS, no barriers. One wave per block; wave = 32 pos x 128 oc.
// mfma_f32_32x32x16_bf16: A/B lane: row/col = lane&31, k = (lane>>5)*8+i;
// D: col = lane&31, row = (reg&3) + 8*(reg>>2) + 4*(lane>>5).
__global__ __launch_bounds__(64, 3) void socg_main(const float* __restrict__ x,
                                                   const __bf16* __restrict__ wb,
                                                   float* __restrict__ out) {
    const int lane = threadIdx.x;
    const int hi   = lane >> 5;
    const int l31  = lane & 31;

    const int bid  = blockIdx.x;          // 2304 = 8 imgs * 48 * 6
    const int bimg = bid / 288;
    const int rem  = bid - bimg * 288;
    const int h0   = (rem / 6) * 2;       // wave tile: 2 rows x 16 cols, all 128 oc
    const int w0   = (rem % 6) * 16;

    // lane's single position
    const int hA = h0 + (l31 >> 4);
    const int wA = w0 + (l31 & 15);

    int   off[9];
    float msk[9];
#pragma unroll
    for (int rr = 0; rr < 3; rr++)
#pragma unroll
        for (int cc = 0; cc < 3; cc++) {
            int hh = hA - 1 + rr, ww = wA - 1 + cc;
            bool ok = ((unsigned)hh < HW) && ((unsigned)ww < HW);
            int hc = hh < 0 ? 0 : (hh > HW-1 ? HW-1 : hh);
            int wc = ww < 0 ? 0 : (ww > HW-1 ? HW-1 : ww);
            off[rr*3 + cc] = hc * HW + wc;
            msk[rr*3 + cc] = ok ? 1.f : 0.f;
        }

    const float* xb = x + (size_t)bimg * CIN * HW * HW;

    f32x16 acc[4];
#pragma unroll
    for (int os = 0; os < 4; os++)
#pragma unroll
        for (int r = 0; r < 16; r++) acc[os][r] = 0.f;

    float rA[9], rB[9];
#pragma unroll
    for (int i = 0; i < 9; i++) rA[i] = xb[off[i]];   // patches for c = 0

    auto body = [&](float (&rc)[9], float (&rn)[9], int c) {
        const __bf16* wc_ = wb + (size_t)c * 8192;
        // A-frags for kc = 0,1 (hoisted: feature build hides the latency)
        bf16x8 A01[2][4];
#pragma unroll
        for (int kc = 0; kc < 2; kc++)
#pragma unroll
            for (int os = 0; os < 4; os++)
                A01[kc][os] = *(const bf16x8*)(wc_ + (kc*2 + hi)*1024
                                               + (os*32 + l31)*8);
        // prefetch next channel's 3x3 window
        if (c + 1 < CIN) {
            const float* xn = xb + (size_t)(c + 1) * HW * HW;
#pragma unroll
            for (int i = 0; i < 9; i++) rn[i] = xn[off[i]];
        }
        float q[9];
#pragma unroll
        for (int i = 0; i < 9; i++) q[i] = rc[i] * msk[i];

        // full 54-feature build, packed to bf16 pairs (one build per pos per channel)
        uint32_t P[32];
#pragma unroll
        for (int j = 0; j < 32; j++) {
            union { __bf16 b[2]; uint32_t u; } pk;
            pk.b[0] = (__bf16)featv(2*j,     q);
            pk.b[1] = (__bf16)featv(2*j + 1, q);
            P[j] = pk.u;
        }

        // kc = 0
        {
            bf16x8 tb = selpair(P, 0, hi);
#pragma unroll
            for (int os = 0; os < 4; os++)
                acc[os] = __builtin_amdgcn_mfma_f32_32x32x16_bf16(A01[0][os], tb,
                                                                  acc[os], 0, 0, 0);
        }
        // issue kc = 2,3 loads under kc-0/1 MFMAs
        bf16x8 A23[2][4];
#pragma unroll
        for (int kc = 0; kc < 2; kc++)
#pragma unroll
            for (int os = 0; os < 4; os++)
                A23[kc][os] = *(const bf16x8*)(wc_ + ((kc+2)*2 + hi)*1024
                                               + (os*32 + l31)*8);
        // kc = 1
        {
            bf16x8 tb = selpair(P, 1, hi);
#pragma unroll
            for (int os = 0; os < 4; os++)
                acc[os] = __builtin_amdgcn_mfma_f32_32x32x16_bf16(A01[1][os], tb,
                                                                  acc[os], 0, 0, 0);
        }
        // kc = 2
        {
            bf16x8 tb = selpair(P, 2, hi);
#pragma unroll
            for (int os = 0; os < 4; os++)
                acc[os] = __builtin_amdgcn_mfma_f32_32x32x16_bf16(A23[0][os], tb,
                                                                  acc[os], 0, 0, 0);
        }
        // kc = 3
        {
            bf16x8 tb = selpair(P, 3, hi);
#pragma unroll
            for (int os = 0; os < 4; os++)
                acc[os] = __builtin_amdgcn_mfma_f32_32x32x16_bf16(A23[1][os], tb,
                                                                  acc[os], 0, 0, 0);
        }
    };

    for (int c2 = 0; c2 < CIN; c2 += 2) {
        body(rA, rB, c2);
        body(rB, rA, c2 + 1);
    }

    // epilogue: D col = pos (lane&31), row = (r&3) + 8*(r>>2) + 4*hi
#pragma unroll
    for (int os = 0; os < 4; os++)
#pragma unroll
        for (int r = 0; r < 16; r++) {
            int oc = os*32 + (r & 3) + 8*(r >> 2) + 4*hi;
            out[(((size_t)bimg*OCH + oc)*HW + hA)*HW + wA] = acc[os][r];
        }
}

extern "C" void kernel_launch(void* const* d_in, const int* in_sizes, int n_in,
                              void* d_out, int out_size, void* d_ws, size_t ws_size,
                              hipStream_t stream) {
    const float* x = (const float*)d_in[0];
    const float* w = (const float*)d_in[1];
    float* out = (float*)d_out;
    __bf16* wbf = (__bf16*)d_ws;   // 64*8192*2 = 1 MiB
    hipLaunchKernelGGL(prep_w, dim3(1024), dim3(256), 0, stream, w, wbf);
    hipLaunchKernelGGL(socg_main, dim3(2304), dim3(64), 0, stream, x, wbf, out);
}